// Round 4
// baseline (1029.397 us; speedup 1.0000x reference)
//
#include <hip/hip_runtime.h>

#define N_NODES 100000
#define N_EDGES 1600000
#define N_GRAPHS 512
#define F 128
#define N_CONVS 4
#define SCAN_NBLK ((N_NODES + 1023) / 1024)   // 98

__device__ __forceinline__ float4 fma4(float w, float4 v, float4 a) {
    a.x = fmaf(w, v.x, a.x); a.y = fmaf(w, v.y, a.y);
    a.z = fmaf(w, v.z, a.z); a.w = fmaf(w, v.w, a.w);
    return a;
}

// ---------------- CSR build ----------------

__global__ void count_kernel(const int* __restrict__ dst, int* __restrict__ cnt) {
    int e = blockIdx.x * blockDim.x + threadIdx.x;
    if (e < N_EDGES) atomicAdd(&cnt[dst[e]], 1);
}

__global__ void dinv_kernel(const int* __restrict__ cnt, float* __restrict__ dinv) {
    int n = blockIdx.x * blockDim.x + threadIdx.x;
    if (n < N_NODES) dinv[n] = rsqrtf((float)cnt[n] + 2.0f);  // improved=True: +2 self loop
}

__global__ void scan1_kernel(const int* __restrict__ cnt, int* __restrict__ excl,
                             int* __restrict__ blksum) {
    __shared__ int sums[256];
    int t = threadIdx.x;
    int base = blockIdx.x * 1024 + t * 4;
    int v0 = 0, v1 = 0, v2 = 0, v3 = 0;
    if (base + 0 < N_NODES) v0 = cnt[base + 0];
    if (base + 1 < N_NODES) v1 = cnt[base + 1];
    if (base + 2 < N_NODES) v2 = cnt[base + 2];
    if (base + 3 < N_NODES) v3 = cnt[base + 3];
    int s = v0 + v1 + v2 + v3;
    sums[t] = s;
    __syncthreads();
    for (int off = 1; off < 256; off <<= 1) {
        int y = (t >= off) ? sums[t - off] : 0;
        __syncthreads();
        sums[t] += y;
        __syncthreads();
    }
    int pre = sums[t] - s;
    if (base + 0 < N_NODES) excl[base + 0] = pre;
    if (base + 1 < N_NODES) excl[base + 1] = pre + v0;
    if (base + 2 < N_NODES) excl[base + 2] = pre + v0 + v1;
    if (base + 3 < N_NODES) excl[base + 3] = pre + v0 + v1 + v2;
    if (t == 255) blksum[blockIdx.x] = sums[255];
}

__global__ void scan2_kernel(int* __restrict__ blksum, int nblk) {
    __shared__ int sh[128];
    int t = threadIdx.x;
    int v = (t < nblk) ? blksum[t] : 0;
    sh[t] = v;
    __syncthreads();
    for (int off = 1; off < 128; off <<= 1) {
        int y = (t >= off) ? sh[t - off] : 0;
        __syncthreads();
        sh[t] += y;
        __syncthreads();
    }
    if (t < nblk) blksum[t] = sh[t] - v;
}

__global__ void scan3_kernel(int* __restrict__ rowptr, const int* __restrict__ blksum,
                             int* __restrict__ fill) {
    int t = threadIdx.x;
    int base = blockIdx.x * 1024 + t * 4;
    int off = blksum[blockIdx.x];
#pragma unroll
    for (int i = 0; i < 4; i++) {
        int idx = base + i;
        if (idx < N_NODES) {
            int v = rowptr[idx] + off;
            rowptr[idx] = v;
            fill[idx] = v;
        }
    }
    if (blockIdx.x == 0 && t == 0) rowptr[N_NODES] = N_EDGES;
}

// Fill packed CSR edges[pos] = (src, dinv[src]*dinv[dst]) — ONE 8 B scatter
// per edge (was two 4 B scatters to two arrays -> 2 dirty lines per edge).
__global__ void fill_kernel(const int* __restrict__ src, const int* __restrict__ dst,
                            const float* __restrict__ dinv,
                            int* __restrict__ fill, int2* __restrict__ edges) {
    int e = blockIdx.x * blockDim.x + threadIdx.x;
    if (e < N_EDGES) {
        int d = dst[e];
        int s = src[e];
        int pos = atomicAdd(&fill[d], 1);
        edges[pos] = make_int2(s, __float_as_int(dinv[s] * dinv[d]));
    }
}

// ---------------- GEMM: H = X @ W   (M=100000, K=N=128, fp32) ----------------
// Full W (64 KB) staged in LDS once per block (2 blocks/CU). X read from
// global with half-wave-uniform float4 addresses (1 request per half-wave,
// each row streamed exactly once). 64 rows/block, thread = 8 rows x 4 cols:
// per k4 step 8 X loads + 4 conflict-free ds_read_b128 + 256 VALU cycles.

__global__ __launch_bounds__(256) void gemm_kernel(const float* __restrict__ X,
                                                   const float* __restrict__ W,
                                                   float* __restrict__ H) {
    __shared__ float4 wlds[4096];   // [k][n4]: idx = k*32 + n4  (64 KB)
    int t = threadIdx.x;
    const float4* W4 = (const float4*)W;
#pragma unroll
    for (int i = 0; i < 16; i++) wlds[i * 256 + t] = W4[i * 256 + t];
    __syncthreads();

    int cg = t & 31;           // output col group (4 cols)
    int rg = t >> 5;           // half-wave id (0..7), owns 8 rows
    int row0 = blockIdx.x * 64 + rg * 8;
    const float4* X4 = (const float4*)X;   // [row][k4]: idx = row*32 + k4

    float4 acc[8];
    size_t base[8];
#pragma unroll
    for (int i = 0; i < 8; i++) {
        acc[i] = make_float4(0.f, 0.f, 0.f, 0.f);
        int r = row0 + i;
        if (r > N_NODES - 1) r = N_NODES - 1;   // clamp: loads always valid
        base[i] = (size_t)r * 32;
    }

#pragma unroll 2
    for (int k4 = 0; k4 < 32; k4++) {
        float4 xv[8];
#pragma unroll
        for (int i = 0; i < 8; i++) xv[i] = X4[base[i] + k4];
        float4 w0 = wlds[(k4 * 4 + 0) * 32 + cg];
        float4 w1 = wlds[(k4 * 4 + 1) * 32 + cg];
        float4 w2 = wlds[(k4 * 4 + 2) * 32 + cg];
        float4 w3 = wlds[(k4 * 4 + 3) * 32 + cg];
#pragma unroll
        for (int i = 0; i < 8; i++) {
            acc[i] = fma4(xv[i].x, w0, acc[i]);
            acc[i] = fma4(xv[i].y, w1, acc[i]);
            acc[i] = fma4(xv[i].z, w2, acc[i]);
            acc[i] = fma4(xv[i].w, w3, acc[i]);
        }
    }

    float4* H4 = (float4*)H;
#pragma unroll
    for (int i = 0; i < 8; i++) {
        int r = row0 + i;
        if (r < N_NODES) H4[(size_t)r * 32 + cg] = acc[i];
    }
}

// ---------------- Aggregation: x_out = relu(agg + 2*dinv^2*h + b) ----------------
// One wave per node; lane halves process even/odd edges; 8 predicated slots
// per half per iteration; packed (col,ew) read as one int2.

__global__ __launch_bounds__(256) void agg_kernel(const float4* __restrict__ H4,
                                                  const int* __restrict__ rowptr,
                                                  const int2* __restrict__ edges,
                                                  const float* __restrict__ dinv,
                                                  const float4* __restrict__ bias4,
                                                  float4* __restrict__ Xo4) {
    int node = blockIdx.x * 4 + (threadIdx.x >> 6);
    if (node >= N_NODES) return;
    int lane = threadIdx.x & 63;
    int cg = lane & 31;
    int h = lane >> 5;

    int lo = rowptr[node];
    int hi = rowptr[node + 1];
    int him1 = hi - 1;

    float4 a[4];
#pragma unroll
    for (int j = 0; j < 4; j++) a[j] = make_float4(0.f, 0.f, 0.f, 0.f);

    for (int i = lo + h; i < hi; i += 16) {
        int s[8]; float w[8]; float4 v[8];
#pragma unroll
        for (int j = 0; j < 8; j++) {
            int ij = i + 2 * j;
            int cj = (ij < him1) ? ij : him1;   // clamp: load always valid
            int2 e = edges[cj];
            s[j] = e.x;
            w[j] = (ij < hi) ? __int_as_float(e.y) : 0.f;
        }
#pragma unroll
        for (int j = 0; j < 8; j++) v[j] = H4[(size_t)s[j] * 32 + cg];
#pragma unroll
        for (int j = 0; j < 8; j++) a[j & 3] = fma4(w[j], v[j], a[j & 3]);
    }

    float4 a0;
    a0.x = (a[0].x + a[1].x) + (a[2].x + a[3].x);
    a0.y = (a[0].y + a[1].y) + (a[2].y + a[3].y);
    a0.z = (a[0].z + a[1].z) + (a[2].z + a[3].z);
    a0.w = (a[0].w + a[1].w) + (a[2].w + a[3].w);

    a0.x += __shfl_down(a0.x, 32, 64);
    a0.y += __shfl_down(a0.y, 32, 64);
    a0.z += __shfl_down(a0.z, 32, 64);
    a0.w += __shfl_down(a0.w, 32, 64);

    if (h == 0) {
        float dn = dinv[node];
        float sw = 2.0f * dn * dn;
        float4 hv = H4[(size_t)node * 32 + cg];
        float4 bv = bias4[cg];
        float4 r;
        r.x = fmaxf(fmaf(sw, hv.x, a0.x) + bv.x, 0.f);
        r.y = fmaxf(fmaf(sw, hv.y, a0.y) + bv.y, 0.f);
        r.z = fmaxf(fmaf(sw, hv.z, a0.z) + bv.z, 0.f);
        r.w = fmaxf(fmaf(sw, hv.w, a0.w) + bv.w, 0.f);
        Xo4[(size_t)node * 32 + cg] = r;
    }
}

// ---------------- Fused mean-pool + FC1(relu) + FC2 ----------------

__global__ __launch_bounds__(256) void pool_fc_kernel(const float* __restrict__ x,
                                                      const int* __restrict__ batch,
                                                      const float* __restrict__ fc1w,
                                                      const float* __restrict__ fc1b,
                                                      const float* __restrict__ fc2w,
                                                      const float* __restrict__ fc2b,
                                                      float* __restrict__ out) {
    __shared__ float part[2][F];
    __shared__ float pooled[F];
    __shared__ int bnd[2];
    __shared__ float red[2];
    int g = blockIdx.x, t = threadIdx.x;
    int c = t & 127, hlf = t >> 7;

    if (t < 2) {
        int target = g + t;
        int lo = 0, hi = N_NODES;
        while (lo < hi) {
            int m = (lo + hi) >> 1;
            if (batch[m] < target) lo = m + 1;
            else hi = m;
        }
        bnd[t] = lo;
    }
    __syncthreads();
    int lo = bnd[0], hi = bnd[1];

    float s = 0.f;
    int n = lo + hlf;
    for (; n + 6 < hi; n += 8) {
        float v0 = x[(size_t)n * F + c];
        float v1 = x[(size_t)(n + 2) * F + c];
        float v2 = x[(size_t)(n + 4) * F + c];
        float v3 = x[(size_t)(n + 6) * F + c];
        s += (v0 + v1) + (v2 + v3);
    }
    for (; n < hi; n += 2) s += x[(size_t)n * F + c];
    part[hlf][c] = s;
    __syncthreads();

    if (t < F) {
        float cntf = fmaxf((float)(hi - lo), 1.0f);
        pooled[c] = (part[0][c] + part[1][c]) / cntf;
    }
    __syncthreads();

    if (t < F) {
        float acc = fc1b[t];
#pragma unroll 4
        for (int k = 0; k < F; k++) acc = fmaf(pooled[k], fc1w[k * F + t], acc);
        acc = fmaxf(acc, 0.f);

        float p = acc * fc2w[t];
#pragma unroll
        for (int o = 32; o > 0; o >>= 1) p += __shfl_down(p, o, 64);
        if ((t & 63) == 0) red[t >> 6] = p;
    }
    __syncthreads();
    if (t == 0) out[g] = red[0] + red[1] + fc2b[0];
}

// ---------------- launch ----------------

extern "C" void kernel_launch(void* const* d_in, const int* in_sizes, int n_in,
                              void* d_out, int out_size, void* d_ws, size_t ws_size,
                              hipStream_t stream) {
    const float* x_in   = (const float*)d_in[0];
    const int*   eidx   = (const int*)d_in[1];
    const int*   batch  = (const int*)d_in[2];
    const float* conv_w = (const float*)d_in[4];
    const float* conv_b = (const float*)d_in[5];
    const float* fc1w   = (const float*)d_in[6];
    const float* fc1b   = (const float*)d_in[7];
    const float* fc2w   = (const float*)d_in[8];
    const float* fc2b   = (const float*)d_in[9];
    float* out = (float*)d_out;

    const int* src = eidx;
    const int* dst = eidx + N_EDGES;

    char* ws = (char*)d_ws;
    size_t off = 0;
    auto alloc = [&](size_t bytes) -> char* {
        char* p = ws + off;
        off += (bytes + 255) & ~(size_t)255;
        return p;
    };
    float* bufA  = (float*)alloc((size_t)N_NODES * F * 4);   // 51.2 MB
    float* bufB  = (float*)alloc((size_t)N_NODES * F * 4);   // 51.2 MB
    float* dinv  = (float*)alloc((size_t)N_NODES * 4);
    int*   cnt   = (int*)alloc((size_t)N_NODES * 4);
    int*   rowp  = (int*)alloc((size_t)(N_NODES + 1) * 4);
    int*   fill  = (int*)alloc((size_t)N_NODES * 4);
    int2*  edges = (int2*)alloc((size_t)N_EDGES * 8);        // 12.8 MB packed
    int*   blks  = (int*)alloc(128 * 4);
    (void)ws_size; (void)in_sizes; (void)n_in; (void)out_size;

    // --- CSR build (once; reused by all 4 layers) ---
    hipMemsetAsync(cnt, 0, (size_t)N_NODES * 4, stream);
    count_kernel<<<(N_EDGES + 255) / 256, 256, 0, stream>>>(dst, cnt);
    dinv_kernel<<<(N_NODES + 255) / 256, 256, 0, stream>>>(cnt, dinv);
    scan1_kernel<<<SCAN_NBLK, 256, 0, stream>>>(cnt, rowp, blks);
    scan2_kernel<<<1, 128, 0, stream>>>(blks, SCAN_NBLK);
    scan3_kernel<<<SCAN_NBLK, 256, 0, stream>>>(rowp, blks, fill);
    fill_kernel<<<(N_EDGES + 255) / 256, 256, 0, stream>>>(src, dst, dinv, fill, edges);

    // --- 4 GCN layers ---
    const float* cur = x_in;
    for (int L = 0; L < N_CONVS; L++) {
        gemm_kernel<<<(N_NODES + 63) / 64, 256, 0, stream>>>(
            cur, conv_w + (size_t)L * F * F, bufB);
        agg_kernel<<<(N_NODES + 3) / 4, 256, 0, stream>>>(
            (const float4*)bufB, rowp, edges, dinv,
            (const float4*)(conv_b + (size_t)L * F), (float4*)bufA);
        cur = bufA;
    }

    // --- mean-pool + FC head ---
    pool_fc_kernel<<<N_GRAPHS, 256, 0, stream>>>(bufA, batch, fc1w, fc1b, fc2w, fc2b, out);
}

// Round 5
// 951.314 us; speedup vs baseline: 1.0821x; 1.0821x over previous
//
#include <hip/hip_runtime.h>

#define N_NODES 100000
#define N_EDGES 1600000
#define N_GRAPHS 512
#define F 128
#define N_CONVS 4
#define SCAN_NBLK ((N_NODES + 1023) / 1024)   // 98
#define FILL_BLOCKS ((N_EDGES + 255) / 256)   // 6250
#define GEMM64_BLOCKS ((N_NODES + 63) / 64)   // 1563
#define GEMM128_BLOCKS ((N_NODES + 127) / 128) // 782

__device__ __forceinline__ float4 fma4(float w, float4 v, float4 a) {
    a.x = fmaf(w, v.x, a.x); a.y = fmaf(w, v.y, a.y);
    a.z = fmaf(w, v.z, a.z); a.w = fmaf(w, v.w, a.w);
    return a;
}

// ---------------- CSR build ----------------

__global__ void count_kernel(const int* __restrict__ dst, int* __restrict__ cnt) {
    int e = blockIdx.x * blockDim.x + threadIdx.x;
    if (e < N_EDGES) atomicAdd(&cnt[dst[e]], 1);
}

__global__ void dinv_kernel(const int* __restrict__ cnt, float* __restrict__ dinv) {
    int n = blockIdx.x * blockDim.x + threadIdx.x;
    if (n < N_NODES) dinv[n] = rsqrtf((float)cnt[n] + 2.0f);  // improved=True: +2 self loop
}

__global__ void scan1_kernel(const int* __restrict__ cnt, int* __restrict__ excl,
                             int* __restrict__ blksum) {
    __shared__ int sums[256];
    int t = threadIdx.x;
    int base = blockIdx.x * 1024 + t * 4;
    int v0 = 0, v1 = 0, v2 = 0, v3 = 0;
    if (base + 0 < N_NODES) v0 = cnt[base + 0];
    if (base + 1 < N_NODES) v1 = cnt[base + 1];
    if (base + 2 < N_NODES) v2 = cnt[base + 2];
    if (base + 3 < N_NODES) v3 = cnt[base + 3];
    int s = v0 + v1 + v2 + v3;
    sums[t] = s;
    __syncthreads();
    for (int off = 1; off < 256; off <<= 1) {
        int y = (t >= off) ? sums[t - off] : 0;
        __syncthreads();
        sums[t] += y;
        __syncthreads();
    }
    int pre = sums[t] - s;
    if (base + 0 < N_NODES) excl[base + 0] = pre;
    if (base + 1 < N_NODES) excl[base + 1] = pre + v0;
    if (base + 2 < N_NODES) excl[base + 2] = pre + v0 + v1;
    if (base + 3 < N_NODES) excl[base + 3] = pre + v0 + v1 + v2;
    if (t == 255) blksum[blockIdx.x] = sums[255];
}

__global__ void scan2_kernel(int* __restrict__ blksum, int nblk) {
    __shared__ int sh[128];
    int t = threadIdx.x;
    int v = (t < nblk) ? blksum[t] : 0;
    sh[t] = v;
    __syncthreads();
    for (int off = 1; off < 128; off <<= 1) {
        int y = (t >= off) ? sh[t - off] : 0;
        __syncthreads();
        sh[t] += y;
        __syncthreads();
    }
    if (t < nblk) blksum[t] = sh[t] - v;
}

__global__ void scan3_kernel(int* __restrict__ rowptr, const int* __restrict__ blksum,
                             int* __restrict__ fill) {
    int t = threadIdx.x;
    int base = blockIdx.x * 1024 + t * 4;
    int off = blksum[blockIdx.x];
#pragma unroll
    for (int i = 0; i < 4; i++) {
        int idx = base + i;
        if (idx < N_NODES) {
            int v = rowptr[idx] + off;
            rowptr[idx] = v;
            fill[idx] = v;
        }
    }
    if (blockIdx.x == 0 && t == 0) rowptr[N_NODES] = N_EDGES;
}

// ---------------- Fused: CSR fill scatter  ||  GEMM layer 0 ----------------
// fill blocks [0, FILL_BLOCKS) are write-scatter-bound (VALU ~0.6%);
// gemm blocks [FILL_BLOCKS, FILL_BLOCKS+GEMM64_BLOCKS) are VALU-bound.
// Independent outputs; both complete before agg_0 (kernel boundary).

__global__ __launch_bounds__(256) void fill_gemm0_kernel(
        const int* __restrict__ src, const int* __restrict__ dst,
        const float* __restrict__ dinv, int* __restrict__ fill,
        int2* __restrict__ edges,
        const float* __restrict__ X, const float* __restrict__ W,
        float* __restrict__ H) {
    __shared__ float xs[64 * 128];   // 32 KB (gemm blocks only)
    int t = threadIdx.x;

    if (blockIdx.x < FILL_BLOCKS) {
        int e = blockIdx.x * 256 + t;
        if (e < N_EDGES) {
            int d = dst[e];
            int s = src[e];
            int pos = atomicAdd(&fill[d], 1);
            edges[pos] = make_int2(s, __float_as_int(dinv[s] * dinv[d]));
        }
        return;
    }

    int gb = blockIdx.x - FILL_BLOCKS;
    int row0b = gb * 64;

#pragma unroll
    for (int i = 0; i < 8; i++) {
        int idx = i * 256 + t;
        int r = idx >> 5;           // 0..63
        int c4 = idx & 31;
        int row = row0b + r;
        if (row > N_NODES - 1) row = N_NODES - 1;
        *(float4*)(&xs[r * 128 + c4 * 4]) = *(const float4*)(X + (size_t)row * F + c4 * 4);
    }
    __syncthreads();

    int cg = t & 31;
    int rg = t >> 5;
    const float4* W4 = (const float4*)W;

    float4 acc[8];
#pragma unroll
    for (int i = 0; i < 8; i++) acc[i] = make_float4(0.f, 0.f, 0.f, 0.f);

#pragma unroll 2
    for (int k4 = 0; k4 < 32; k4++) {
        float4 w0 = W4[(k4 * 4 + 0) * 32 + cg];
        float4 w1 = W4[(k4 * 4 + 1) * 32 + cg];
        float4 w2 = W4[(k4 * 4 + 2) * 32 + cg];
        float4 w3 = W4[(k4 * 4 + 3) * 32 + cg];
#pragma unroll
        for (int i = 0; i < 8; i++) {
            float4 xv = *(const float4*)(&xs[(rg * 8 + i) * 128 + k4 * 4]);
            acc[i] = fma4(xv.x, w0, acc[i]);
            acc[i] = fma4(xv.y, w1, acc[i]);
            acc[i] = fma4(xv.z, w2, acc[i]);
            acc[i] = fma4(xv.w, w3, acc[i]);
        }
    }

    float4* H4 = (float4*)H;
#pragma unroll
    for (int i = 0; i < 8; i++) {
        int r = row0b + rg * 8 + i;
        if (r < N_NODES) H4[(size_t)r * 32 + cg] = acc[i];
    }
}

// ---------------- GEMM (layers 1-3): 128 rows/block, 16 rows x 4 cols/thread ----
// X tile (64 KB) in LDS, uniform ds_read_b128 broadcast; W streamed from L2.
// Per k4: 512 VALU-cyc FMA vs 16 ds_read + 4 W loads -> VALU-bound.

__global__ __launch_bounds__(256) void gemm128_kernel(const float* __restrict__ X,
                                                      const float* __restrict__ W,
                                                      float* __restrict__ H) {
    __shared__ float xs[128 * 128];   // 64 KB
    int t = threadIdx.x;
    int row0b = blockIdx.x * 128;

#pragma unroll
    for (int i = 0; i < 16; i++) {
        int idx = i * 256 + t;
        int r = idx >> 5;           // 0..127
        int c4 = idx & 31;
        int row = row0b + r;
        if (row > N_NODES - 1) row = N_NODES - 1;
        *(float4*)(&xs[r * 128 + c4 * 4]) = *(const float4*)(X + (size_t)row * F + c4 * 4);
    }
    __syncthreads();

    int cg = t & 31;
    int rg = t >> 5;                 // 8 half-waves x 16 rows
    int rowbase = rg * 16;
    const float4* W4 = (const float4*)W;

    float4 acc[16];
#pragma unroll
    for (int i = 0; i < 16; i++) acc[i] = make_float4(0.f, 0.f, 0.f, 0.f);

#pragma unroll 2
    for (int k4 = 0; k4 < 32; k4++) {
        float4 w0 = W4[(k4 * 4 + 0) * 32 + cg];
        float4 w1 = W4[(k4 * 4 + 1) * 32 + cg];
        float4 w2 = W4[(k4 * 4 + 2) * 32 + cg];
        float4 w3 = W4[(k4 * 4 + 3) * 32 + cg];
#pragma unroll
        for (int i = 0; i < 16; i++) {
            float4 xv = *(const float4*)(&xs[(rowbase + i) * 128 + k4 * 4]);
            acc[i] = fma4(xv.x, w0, acc[i]);
            acc[i] = fma4(xv.y, w1, acc[i]);
            acc[i] = fma4(xv.z, w2, acc[i]);
            acc[i] = fma4(xv.w, w3, acc[i]);
        }
    }

    float4* H4 = (float4*)H;
#pragma unroll
    for (int i = 0; i < 16; i++) {
        int r = row0b + rowbase + i;
        if (r < N_NODES) H4[(size_t)r * 32 + cg] = acc[i];
    }
}

// ---------------- Aggregation: x_out = relu(agg + 2*dinv^2*h + b) ----------------

__global__ __launch_bounds__(256) void agg_kernel(const float4* __restrict__ H4,
                                                  const int* __restrict__ rowptr,
                                                  const int2* __restrict__ edges,
                                                  const float* __restrict__ dinv,
                                                  const float4* __restrict__ bias4,
                                                  float4* __restrict__ Xo4) {
    int node = blockIdx.x * 4 + (threadIdx.x >> 6);
    if (node >= N_NODES) return;
    int lane = threadIdx.x & 63;
    int cg = lane & 31;
    int h = lane >> 5;

    int lo = rowptr[node];
    int hi = rowptr[node + 1];
    int him1 = hi - 1;

    float4 a[4];
#pragma unroll
    for (int j = 0; j < 4; j++) a[j] = make_float4(0.f, 0.f, 0.f, 0.f);

    for (int i = lo + h; i < hi; i += 16) {
        int s[8]; float w[8]; float4 v[8];
#pragma unroll
        for (int j = 0; j < 8; j++) {
            int ij = i + 2 * j;
            int cj = (ij < him1) ? ij : him1;
            int2 e = edges[cj];
            s[j] = e.x;
            w[j] = (ij < hi) ? __int_as_float(e.y) : 0.f;
        }
#pragma unroll
        for (int j = 0; j < 8; j++) v[j] = H4[(size_t)s[j] * 32 + cg];
#pragma unroll
        for (int j = 0; j < 8; j++) a[j & 3] = fma4(w[j], v[j], a[j & 3]);
    }

    float4 a0;
    a0.x = (a[0].x + a[1].x) + (a[2].x + a[3].x);
    a0.y = (a[0].y + a[1].y) + (a[2].y + a[3].y);
    a0.z = (a[0].z + a[1].z) + (a[2].z + a[3].z);
    a0.w = (a[0].w + a[1].w) + (a[2].w + a[3].w);

    a0.x += __shfl_down(a0.x, 32, 64);
    a0.y += __shfl_down(a0.y, 32, 64);
    a0.z += __shfl_down(a0.z, 32, 64);
    a0.w += __shfl_down(a0.w, 32, 64);

    if (h == 0) {
        float dn = dinv[node];
        float sw = 2.0f * dn * dn;
        float4 hv = H4[(size_t)node * 32 + cg];
        float4 bv = bias4[cg];
        float4 r;
        r.x = fmaxf(fmaf(sw, hv.x, a0.x) + bv.x, 0.f);
        r.y = fmaxf(fmaf(sw, hv.y, a0.y) + bv.y, 0.f);
        r.z = fmaxf(fmaf(sw, hv.z, a0.z) + bv.z, 0.f);
        r.w = fmaxf(fmaf(sw, hv.w, a0.w) + bv.w, 0.f);
        Xo4[(size_t)node * 32 + cg] = r;
    }
}

// ---------------- Fused mean-pool + FC1(relu) + FC2 ----------------

__global__ __launch_bounds__(256) void pool_fc_kernel(const float* __restrict__ x,
                                                      const int* __restrict__ batch,
                                                      const float* __restrict__ fc1w,
                                                      const float* __restrict__ fc1b,
                                                      const float* __restrict__ fc2w,
                                                      const float* __restrict__ fc2b,
                                                      float* __restrict__ out) {
    __shared__ float part[2][F];
    __shared__ float pooled[F];
    __shared__ int bnd[2];
    __shared__ float red[2];
    int g = blockIdx.x, t = threadIdx.x;
    int c = t & 127, hlf = t >> 7;

    if (t < 2) {
        int target = g + t;
        int lo = 0, hi = N_NODES;
        while (lo < hi) {
            int m = (lo + hi) >> 1;
            if (batch[m] < target) lo = m + 1;
            else hi = m;
        }
        bnd[t] = lo;
    }
    __syncthreads();
    int lo = bnd[0], hi = bnd[1];

    float s = 0.f;
    int n = lo + hlf;
    for (; n + 6 < hi; n += 8) {
        float v0 = x[(size_t)n * F + c];
        float v1 = x[(size_t)(n + 2) * F + c];
        float v2 = x[(size_t)(n + 4) * F + c];
        float v3 = x[(size_t)(n + 6) * F + c];
        s += (v0 + v1) + (v2 + v3);
    }
    for (; n < hi; n += 2) s += x[(size_t)n * F + c];
    part[hlf][c] = s;
    __syncthreads();

    if (t < F) {
        float cntf = fmaxf((float)(hi - lo), 1.0f);
        pooled[c] = (part[0][c] + part[1][c]) / cntf;
    }
    __syncthreads();

    if (t < F) {
        float acc = fc1b[t];
#pragma unroll 4
        for (int k = 0; k < F; k++) acc = fmaf(pooled[k], fc1w[k * F + t], acc);
        acc = fmaxf(acc, 0.f);

        float p = acc * fc2w[t];
#pragma unroll
        for (int o = 32; o > 0; o >>= 1) p += __shfl_down(p, o, 64);
        if ((t & 63) == 0) red[t >> 6] = p;
    }
    __syncthreads();
    if (t == 0) out[g] = red[0] + red[1] + fc2b[0];
}

// ---------------- launch ----------------

extern "C" void kernel_launch(void* const* d_in, const int* in_sizes, int n_in,
                              void* d_out, int out_size, void* d_ws, size_t ws_size,
                              hipStream_t stream) {
    const float* x_in   = (const float*)d_in[0];
    const int*   eidx   = (const int*)d_in[1];
    const int*   batch  = (const int*)d_in[2];
    const float* conv_w = (const float*)d_in[4];
    const float* conv_b = (const float*)d_in[5];
    const float* fc1w   = (const float*)d_in[6];
    const float* fc1b   = (const float*)d_in[7];
    const float* fc2w   = (const float*)d_in[8];
    const float* fc2b   = (const float*)d_in[9];
    float* out = (float*)d_out;

    const int* src = eidx;
    const int* dst = eidx + N_EDGES;

    char* ws = (char*)d_ws;
    size_t off = 0;
    auto alloc = [&](size_t bytes) -> char* {
        char* p = ws + off;
        off += (bytes + 255) & ~(size_t)255;
        return p;
    };
    float* bufA  = (float*)alloc((size_t)N_NODES * F * 4);   // 51.2 MB
    float* bufB  = (float*)alloc((size_t)N_NODES * F * 4);   // 51.2 MB
    float* dinv  = (float*)alloc((size_t)N_NODES * 4);
    int*   cnt   = (int*)alloc((size_t)N_NODES * 4);
    int*   rowp  = (int*)alloc((size_t)(N_NODES + 1) * 4);
    int*   fill  = (int*)alloc((size_t)N_NODES * 4);
    int2*  edges = (int2*)alloc((size_t)N_EDGES * 8);        // 12.8 MB packed
    int*   blks  = (int*)alloc(128 * 4);
    (void)ws_size; (void)in_sizes; (void)n_in; (void)out_size;

    // --- CSR prep (count/scan) ---
    hipMemsetAsync(cnt, 0, (size_t)N_NODES * 4, stream);
    count_kernel<<<(N_EDGES + 255) / 256, 256, 0, stream>>>(dst, cnt);
    dinv_kernel<<<(N_NODES + 255) / 256, 256, 0, stream>>>(cnt, dinv);
    scan1_kernel<<<SCAN_NBLK, 256, 0, stream>>>(cnt, rowp, blks);
    scan2_kernel<<<1, 128, 0, stream>>>(blks, SCAN_NBLK);
    scan3_kernel<<<SCAN_NBLK, 256, 0, stream>>>(rowp, blks, fill);

    // --- fused: CSR fill scatter || GEMM layer 0 ---
    fill_gemm0_kernel<<<FILL_BLOCKS + GEMM64_BLOCKS, 256, 0, stream>>>(
        src, dst, dinv, fill, edges, x_in, conv_w, bufB);
    agg_kernel<<<(N_NODES + 3) / 4, 256, 0, stream>>>(
        (const float4*)bufB, rowp, edges, dinv,
        (const float4*)conv_b, (float4*)bufA);

    // --- layers 1-3 ---
    for (int L = 1; L < N_CONVS; L++) {
        gemm128_kernel<<<GEMM128_BLOCKS, 256, 0, stream>>>(
            bufA, conv_w + (size_t)L * F * F, bufB);
        agg_kernel<<<(N_NODES + 3) / 4, 256, 0, stream>>>(
            (const float4*)bufB, rowp, edges, dinv,
            (const float4*)(conv_b + (size_t)L * F), (float4*)bufA);
    }

    // --- mean-pool + FC head ---
    pool_fc_kernel<<<N_GRAPHS, 256, 0, stream>>>(bufA, batch, fc1w, fc1b, fc2w, fc2b, out);
}

// Round 6
// 882.206 us; speedup vs baseline: 1.1668x; 1.0783x over previous
//
#include <hip/hip_runtime.h>

#define N_NODES 100000
#define N_EDGES 1600000
#define N_GRAPHS 512
#define F 128
#define N_CONVS 4
#define SCAN_NBLK ((N_NODES + 1023) / 1024)   // 98
#define FILL_BLOCKS ((N_EDGES + 255) / 256)   // 6250
#define GEMM64_BLOCKS ((N_NODES + 63) / 64)   // 1563

// packed W2 row stride: 256 bf16 (hi/lo interleaved) padded to 264 = 132 dwords
#define W2_STRIDE 132
#define W2_LAYER (128 * W2_STRIDE)            // dwords per layer

typedef __attribute__((ext_vector_type(8))) short short8;   // 8 bf16 (4 VGPRs)
typedef __attribute__((ext_vector_type(4))) float f32x4;

union FragU { uint4 u; short8 v; };

__device__ __forceinline__ float4 fma4(float w, float4 v, float4 a) {
    a.x = fmaf(w, v.x, a.x); a.y = fmaf(w, v.y, a.y);
    a.z = fmaf(w, v.z, a.z); a.w = fmaf(w, v.w, a.w);
    return a;
}

// split f into truncated-bf16 hi/lo, packed (hi in low16, lo in high16).
// hi = trunc_bf16(f); lo = trunc_bf16(f - hi);  |f - hi - lo| <= 2^-16 |f|
__device__ __forceinline__ unsigned int pack_hilo(float f) {
    unsigned int u = __float_as_uint(f);
    unsigned int hb = u & 0xFFFF0000u;
    float d = f - __uint_as_float(hb);
    unsigned int lb = __float_as_uint(d) >> 16;
    return (u >> 16) | (lb << 16);
}

// ---------------- CSR build ----------------

__global__ void count_kernel(const int* __restrict__ dst, int* __restrict__ cnt) {
    int e = blockIdx.x * blockDim.x + threadIdx.x;
    if (e < N_EDGES) atomicAdd(&cnt[dst[e]], 1);
}

__global__ void dinv_kernel(const int* __restrict__ cnt, float* __restrict__ dinv) {
    int n = blockIdx.x * blockDim.x + threadIdx.x;
    if (n < N_NODES) dinv[n] = rsqrtf((float)cnt[n] + 2.0f);  // improved=True: +2 self loop
}

__global__ void scan1_kernel(const int* __restrict__ cnt, int* __restrict__ excl,
                             int* __restrict__ blksum) {
    __shared__ int sums[256];
    int t = threadIdx.x;
    int base = blockIdx.x * 1024 + t * 4;
    int v0 = 0, v1 = 0, v2 = 0, v3 = 0;
    if (base + 0 < N_NODES) v0 = cnt[base + 0];
    if (base + 1 < N_NODES) v1 = cnt[base + 1];
    if (base + 2 < N_NODES) v2 = cnt[base + 2];
    if (base + 3 < N_NODES) v3 = cnt[base + 3];
    int s = v0 + v1 + v2 + v3;
    sums[t] = s;
    __syncthreads();
    for (int off = 1; off < 256; off <<= 1) {
        int y = (t >= off) ? sums[t - off] : 0;
        __syncthreads();
        sums[t] += y;
        __syncthreads();
    }
    int pre = sums[t] - s;
    if (base + 0 < N_NODES) excl[base + 0] = pre;
    if (base + 1 < N_NODES) excl[base + 1] = pre + v0;
    if (base + 2 < N_NODES) excl[base + 2] = pre + v0 + v1;
    if (base + 3 < N_NODES) excl[base + 3] = pre + v0 + v1 + v2;
    if (t == 255) blksum[blockIdx.x] = sums[255];
}

__global__ void scan2_kernel(int* __restrict__ blksum, int nblk) {
    __shared__ int sh[128];
    int t = threadIdx.x;
    int v = (t < nblk) ? blksum[t] : 0;
    sh[t] = v;
    __syncthreads();
    for (int off = 1; off < 128; off <<= 1) {
        int y = (t >= off) ? sh[t - off] : 0;
        __syncthreads();
        sh[t] += y;
        __syncthreads();
    }
    if (t < nblk) blksum[t] = sh[t] - v;
}

__global__ void scan3_kernel(int* __restrict__ rowptr, const int* __restrict__ blksum,
                             int* __restrict__ fill) {
    int t = threadIdx.x;
    int base = blockIdx.x * 1024 + t * 4;
    int off = blksum[blockIdx.x];
#pragma unroll
    for (int i = 0; i < 4; i++) {
        int idx = base + i;
        if (idx < N_NODES) {
            int v = rowptr[idx] + off;
            rowptr[idx] = v;
            fill[idx] = v;
        }
    }
    if (blockIdx.x == 0 && t == 0) rowptr[N_NODES] = N_EDGES;
}

// ---------------- W pre-pack: conv_w[L][k][n] -> W2g[L][n][132 dwords] ----------------
// dword at [L][n][k] = pack(hi(W[k][n]), lo(W[k][n])) — B-operand friendly layout.

__global__ void wpack_kernel(const float* __restrict__ conv_w, unsigned int* __restrict__ W2g) {
    int idx = blockIdx.x * 256 + threadIdx.x;
    if (idx < N_CONVS * 16384) {
        int L = idx >> 14;
        int e = idx & 16383;
        int k = e >> 7;
        int n = e & 127;
        float f = conv_w[(size_t)L * 16384 + k * 128 + n];
        W2g[(size_t)L * W2_LAYER + n * W2_STRIDE + k] = pack_hilo(f);
    }
}

// ---------------- Fused: CSR fill scatter  ||  GEMM layer 0 (VALU) ----------------

__global__ __launch_bounds__(256) void fill_gemm0_kernel(
        const int* __restrict__ src, const int* __restrict__ dst,
        const float* __restrict__ dinv, int* __restrict__ fill,
        int2* __restrict__ edges,
        const float* __restrict__ X, const float* __restrict__ W,
        float* __restrict__ H) {
    __shared__ float xs[64 * 128];   // 32 KB (gemm blocks only)
    int t = threadIdx.x;

    if (blockIdx.x < FILL_BLOCKS) {
        int e = blockIdx.x * 256 + t;
        if (e < N_EDGES) {
            int d = dst[e];
            int s = src[e];
            int pos = atomicAdd(&fill[d], 1);
            edges[pos] = make_int2(s, __float_as_int(dinv[s] * dinv[d]));
        }
        return;
    }

    int gb = blockIdx.x - FILL_BLOCKS;
    int row0b = gb * 64;

#pragma unroll
    for (int i = 0; i < 8; i++) {
        int idx = i * 256 + t;
        int r = idx >> 5;
        int c4 = idx & 31;
        int row = row0b + r;
        if (row > N_NODES - 1) row = N_NODES - 1;
        *(float4*)(&xs[r * 128 + c4 * 4]) = *(const float4*)(X + (size_t)row * F + c4 * 4);
    }
    __syncthreads();

    int cg = t & 31;
    int rg = t >> 5;
    const float4* W4 = (const float4*)W;

    float4 acc[8];
#pragma unroll
    for (int i = 0; i < 8; i++) acc[i] = make_float4(0.f, 0.f, 0.f, 0.f);

#pragma unroll 2
    for (int k4 = 0; k4 < 32; k4++) {
        float4 w0 = W4[(k4 * 4 + 0) * 32 + cg];
        float4 w1 = W4[(k4 * 4 + 1) * 32 + cg];
        float4 w2 = W4[(k4 * 4 + 2) * 32 + cg];
        float4 w3 = W4[(k4 * 4 + 3) * 32 + cg];
#pragma unroll
        for (int i = 0; i < 8; i++) {
            float4 xv = *(const float4*)(&xs[(rg * 8 + i) * 128 + k4 * 4]);
            acc[i] = fma4(xv.x, w0, acc[i]);
            acc[i] = fma4(xv.y, w1, acc[i]);
            acc[i] = fma4(xv.z, w2, acc[i]);
            acc[i] = fma4(xv.w, w3, acc[i]);
        }
    }

    float4* H4 = (float4*)H;
#pragma unroll
    for (int i = 0; i < 8; i++) {
        int r = row0b + rg * 8 + i;
        if (r < N_NODES) H4[(size_t)r * 32 + cg] = acc[i];
    }
}

// ---------------- MFMA GEMM (layers 1-3): H = X @ W via split-bf16 ----------------
// 64 rows/block, 4 waves; wave w computes rows [blk*64+w*16, +16) x all 128 cols
// as 8 C-tiles of 16x16 with mfma_f32_16x16x32_bf16 over doubled K=256
// (positions 2k=hi, 2k+1=lo). Pass 2 rotates each B dword 16 bits (hi<->lo)
// to produce the cross terms. W2 staged in LDS (132-dword row stride).

__global__ __launch_bounds__(256) void gemm_mfma_kernel(const float* __restrict__ X,
                                                        const unsigned int* __restrict__ W2g,
                                                        float* __restrict__ H) {
    __shared__ unsigned int wlds[128 * W2_STRIDE];   // 67584 B
    int t = threadIdx.x;

    {   // stage packed W (16896 dwords) as uint4 copies
        const uint4* s4 = (const uint4*)W2g;
        uint4* d4 = (uint4*)wlds;
#pragma unroll
        for (int i = 0; i < 17; i++) {
            int idx = i * 256 + t;
            if (idx < (128 * W2_STRIDE) / 4) d4[idx] = s4[idx];
        }
    }
    __syncthreads();

    int w = t >> 6;
    int l = t & 63;
    int m = l & 15;        // A row in tile / B col in tile / C col
    int q = l >> 4;        // quad: A/B k-offset q*8, C row-offset q*4
    int rowA = blockIdx.x * 64 + w * 16 + m;
    int rowAc = (rowA > N_NODES - 1) ? (N_NODES - 1) : rowA;
    const float4* X4 = (const float4*)X;

    // A-frags: frag i covers K2 positions i*32+q*8 .. +7  (logical k0 = i*16+q*4)
    uint4 afr[8];
#pragma unroll
    for (int i = 0; i < 8; i++) {
        float4 xv = X4[(size_t)rowAc * 32 + i * 4 + q];
        afr[i].x = pack_hilo(xv.x);
        afr[i].y = pack_hilo(xv.y);
        afr[i].z = pack_hilo(xv.z);
        afr[i].w = pack_hilo(xv.w);
    }

    f32x4 acc[8];
#pragma unroll
    for (int nb = 0; nb < 8; nb++) acc[nb] = (f32x4){0.f, 0.f, 0.f, 0.f};

#pragma unroll
    for (int nb = 0; nb < 8; nb++) {
        const unsigned int* wb = &wlds[(nb * 16 + m) * W2_STRIDE];
#pragma unroll
        for (int i = 0; i < 8; i++) {
            uint4 b = *(const uint4*)(wb + i * 16 + q * 4);
            FragU fa, fb, fr;
            fa.u = afr[i];
            fb.u = b;
            acc[nb] = __builtin_amdgcn_mfma_f32_16x16x32_bf16(fa.v, fb.v, acc[nb], 0, 0, 0);
            fr.u.x = (b.x >> 16) | (b.x << 16);   // hi<->lo swap -> cross terms
            fr.u.y = (b.y >> 16) | (b.y << 16);
            fr.u.z = (b.z >> 16) | (b.z << 16);
            fr.u.w = (b.w >> 16) | (b.w << 16);
            acc[nb] = __builtin_amdgcn_mfma_f32_16x16x32_bf16(fa.v, fr.v, acc[nb], 0, 0, 0);
        }
    }

    // C/D layout: col = lane&15 (=m), row = q*4 + r
    int rbase = blockIdx.x * 64 + w * 16 + q * 4;
#pragma unroll
    for (int nb = 0; nb < 8; nb++) {
#pragma unroll
        for (int r = 0; r < 4; r++) {
            int row = rbase + r;
            if (row < N_NODES) H[(size_t)row * F + nb * 16 + m] = acc[nb][r];
        }
    }
}

// ---------------- Aggregation: x_out = relu(agg + 2*dinv^2*h + b) ----------------

__global__ __launch_bounds__(256) void agg_kernel(const float4* __restrict__ H4,
                                                  const int* __restrict__ rowptr,
                                                  const int2* __restrict__ edges,
                                                  const float* __restrict__ dinv,
                                                  const float4* __restrict__ bias4,
                                                  float4* __restrict__ Xo4) {
    int node = blockIdx.x * 4 + (threadIdx.x >> 6);
    if (node >= N_NODES) return;
    int lane = threadIdx.x & 63;
    int cg = lane & 31;
    int h = lane >> 5;

    int lo = rowptr[node];
    int hi = rowptr[node + 1];
    int him1 = hi - 1;

    float4 a[4];
#pragma unroll
    for (int j = 0; j < 4; j++) a[j] = make_float4(0.f, 0.f, 0.f, 0.f);

    for (int i = lo + h; i < hi; i += 16) {
        int s[8]; float w[8]; float4 v[8];
#pragma unroll
        for (int j = 0; j < 8; j++) {
            int ij = i + 2 * j;
            int cj = (ij < him1) ? ij : him1;
            int2 e = edges[cj];
            s[j] = e.x;
            w[j] = (ij < hi) ? __int_as_float(e.y) : 0.f;
        }
#pragma unroll
        for (int j = 0; j < 8; j++) v[j] = H4[(size_t)s[j] * 32 + cg];
#pragma unroll
        for (int j = 0; j < 8; j++) a[j & 3] = fma4(w[j], v[j], a[j & 3]);
    }

    float4 a0;
    a0.x = (a[0].x + a[1].x) + (a[2].x + a[3].x);
    a0.y = (a[0].y + a[1].y) + (a[2].y + a[3].y);
    a0.z = (a[0].z + a[1].z) + (a[2].z + a[3].z);
    a0.w = (a[0].w + a[1].w) + (a[2].w + a[3].w);

    a0.x += __shfl_down(a0.x, 32, 64);
    a0.y += __shfl_down(a0.y, 32, 64);
    a0.z += __shfl_down(a0.z, 32, 64);
    a0.w += __shfl_down(a0.w, 32, 64);

    if (h == 0) {
        float dn = dinv[node];
        float sw = 2.0f * dn * dn;
        float4 hv = H4[(size_t)node * 32 + cg];
        float4 bv = bias4[cg];
        float4 r;
        r.x = fmaxf(fmaf(sw, hv.x, a0.x) + bv.x, 0.f);
        r.y = fmaxf(fmaf(sw, hv.y, a0.y) + bv.y, 0.f);
        r.z = fmaxf(fmaf(sw, hv.z, a0.z) + bv.z, 0.f);
        r.w = fmaxf(fmaf(sw, hv.w, a0.w) + bv.w, 0.f);
        Xo4[(size_t)node * 32 + cg] = r;
    }
}

// ---------------- Fused mean-pool + FC1(relu) + FC2 ----------------

__global__ __launch_bounds__(256) void pool_fc_kernel(const float* __restrict__ x,
                                                      const int* __restrict__ batch,
                                                      const float* __restrict__ fc1w,
                                                      const float* __restrict__ fc1b,
                                                      const float* __restrict__ fc2w,
                                                      const float* __restrict__ fc2b,
                                                      float* __restrict__ out) {
    __shared__ float part[2][F];
    __shared__ float pooled[F];
    __shared__ int bnd[2];
    __shared__ float red[2];
    int g = blockIdx.x, t = threadIdx.x;
    int c = t & 127, hlf = t >> 7;

    if (t < 2) {
        int target = g + t;
        int lo = 0, hi = N_NODES;
        while (lo < hi) {
            int m = (lo + hi) >> 1;
            if (batch[m] < target) lo = m + 1;
            else hi = m;
        }
        bnd[t] = lo;
    }
    __syncthreads();
    int lo = bnd[0], hi = bnd[1];

    float s = 0.f;
    int n = lo + hlf;
    for (; n + 6 < hi; n += 8) {
        float v0 = x[(size_t)n * F + c];
        float v1 = x[(size_t)(n + 2) * F + c];
        float v2 = x[(size_t)(n + 4) * F + c];
        float v3 = x[(size_t)(n + 6) * F + c];
        s += (v0 + v1) + (v2 + v3);
    }
    for (; n < hi; n += 2) s += x[(size_t)n * F + c];
    part[hlf][c] = s;
    __syncthreads();

    if (t < F) {
        float cntf = fmaxf((float)(hi - lo), 1.0f);
        pooled[c] = (part[0][c] + part[1][c]) / cntf;
    }
    __syncthreads();

    if (t < F) {
        float acc = fc1b[t];
#pragma unroll 4
        for (int k = 0; k < F; k++) acc = fmaf(pooled[k], fc1w[k * F + t], acc);
        acc = fmaxf(acc, 0.f);

        float p = acc * fc2w[t];
#pragma unroll
        for (int o = 32; o > 0; o >>= 1) p += __shfl_down(p, o, 64);
        if ((t & 63) == 0) red[t >> 6] = p;
    }
    __syncthreads();
    if (t == 0) out[g] = red[0] + red[1] + fc2b[0];
}

// ---------------- launch ----------------

extern "C" void kernel_launch(void* const* d_in, const int* in_sizes, int n_in,
                              void* d_out, int out_size, void* d_ws, size_t ws_size,
                              hipStream_t stream) {
    const float* x_in   = (const float*)d_in[0];
    const int*   eidx   = (const int*)d_in[1];
    const int*   batch  = (const int*)d_in[2];
    const float* conv_w = (const float*)d_in[4];
    const float* conv_b = (const float*)d_in[5];
    const float* fc1w   = (const float*)d_in[6];
    const float* fc1b   = (const float*)d_in[7];
    const float* fc2w   = (const float*)d_in[8];
    const float* fc2b   = (const float*)d_in[9];
    float* out = (float*)d_out;

    const int* src = eidx;
    const int* dst = eidx + N_EDGES;

    char* ws = (char*)d_ws;
    size_t off = 0;
    auto alloc = [&](size_t bytes) -> char* {
        char* p = ws + off;
        off += (bytes + 255) & ~(size_t)255;
        return p;
    };
    float* bufA  = (float*)alloc((size_t)N_NODES * F * 4);   // 51.2 MB
    float* bufB  = (float*)alloc((size_t)N_NODES * F * 4);   // 51.2 MB
    float* dinv  = (float*)alloc((size_t)N_NODES * 4);
    int*   cnt   = (int*)alloc((size_t)N_NODES * 4);
    int*   rowp  = (int*)alloc((size_t)(N_NODES + 1) * 4);
    int*   fill  = (int*)alloc((size_t)N_NODES * 4);
    int2*  edges = (int2*)alloc((size_t)N_EDGES * 8);        // 12.8 MB packed
    unsigned int* W2g = (unsigned int*)alloc((size_t)N_CONVS * W2_LAYER * 4);  // 264 KB
    int*   blks  = (int*)alloc(128 * 4);
    (void)ws_size; (void)in_sizes; (void)n_in; (void)out_size;

    // --- CSR prep + W pre-pack ---
    hipMemsetAsync(cnt, 0, (size_t)N_NODES * 4, stream);
    count_kernel<<<(N_EDGES + 255) / 256, 256, 0, stream>>>(dst, cnt);
    dinv_kernel<<<(N_NODES + 255) / 256, 256, 0, stream>>>(cnt, dinv);
    scan1_kernel<<<SCAN_NBLK, 256, 0, stream>>>(cnt, rowp, blks);
    scan2_kernel<<<1, 128, 0, stream>>>(blks, SCAN_NBLK);
    scan3_kernel<<<SCAN_NBLK, 256, 0, stream>>>(rowp, blks, fill);
    wpack_kernel<<<(N_CONVS * 16384 + 255) / 256, 256, 0, stream>>>(conv_w, W2g);

    // --- fused: CSR fill scatter || GEMM layer 0 ---
    fill_gemm0_kernel<<<FILL_BLOCKS + GEMM64_BLOCKS, 256, 0, stream>>>(
        src, dst, dinv, fill, edges, x_in, conv_w, bufB);
    agg_kernel<<<(N_NODES + 3) / 4, 256, 0, stream>>>(
        (const float4*)bufB, rowp, edges, dinv,
        (const float4*)conv_b, (float4*)bufA);

    // --- layers 1-3: MFMA split-bf16 GEMM ---
    for (int L = 1; L < N_CONVS; L++) {
        gemm_mfma_kernel<<<GEMM64_BLOCKS, 256, 0, stream>>>(
            bufA, W2g + (size_t)L * W2_LAYER, bufB);
        agg_kernel<<<(N_NODES + 3) / 4, 256, 0, stream>>>(
            (const float4*)bufB, rowp, edges, dinv,
            (const float4*)(conv_b + (size_t)L * F), (float4*)bufA);
    }

    // --- mean-pool + FC head ---
    pool_fc_kernel<<<N_GRAPHS, 256, 0, stream>>>(bufA, batch, fc1w, fc1b, fc2w, fc2b, out);
}